// Round 3
// baseline (221.725 us; speedup 1.0000x reference)
//
#include <hip/hip_runtime.h>
#include <stdint.h>

// Problem dims (fixed): B=2, S=2048, D=1024, H=16, d_head=64
#define SEQ 2048
#define A_SIZE 4194304   // 2*2048*1024 floats (output 'a'), present follows

typedef short short8 __attribute__((ext_vector_type(8)));
typedef float f32x4 __attribute__((ext_vector_type(4)));

#define AS1 __attribute__((address_space(1)))
#define AS3 __attribute__((address_space(3)))

static __device__ __forceinline__ void async16(const void* g, void* l) {
  __builtin_amdgcn_global_load_lds((const AS1 uint32_t*)g, (AS3 uint32_t*)l, 16, 0, 0);
}

static __device__ __forceinline__ unsigned short f2bf(float f) {
  union { float f; uint32_t u; } v; v.f = f;
  uint32_t u = v.u;
  return (unsigned short)((u + 0x7FFFu + ((u >> 16) & 1u)) >> 16);
}

static __device__ __forceinline__ uint32_t fbits(float f) {
  union { float f; uint32_t u; } v; v.f = f;
  return v.u;
}

// pack two floats to two truncated bf16 in one u32: low=p0, high=p1
static __device__ __forceinline__ uint32_t pack_bf2(float p0, float p1) {
  return __builtin_amdgcn_perm(fbits(p1), fbits(p0), 0x07060302u);
}

// ---------------- convert x -> bf16 (straight) ----------------
__global__ void k_cvt(const float* __restrict__ in, unsigned short* __restrict__ out, int n4) {
  int i = blockIdx.x * blockDim.x + threadIdx.x;
  if (i >= n4) return;
  float4 f = ((const float4*)in)[i];
  ushort4 o;
  o.x = f2bf(f.x); o.y = f2bf(f.y); o.z = f2bf(f.z); o.w = f2bf(f.w);
  ((ushort4*)out)[i] = o;
}

// ------- convert + transpose: in [R][C] f32 -> out [C][R] bf16 -------
__global__ void k_tcvt(const float* __restrict__ in, unsigned short* __restrict__ out,
                       int R, int C) {
  __shared__ unsigned short tile[64][65];
  int c0 = blockIdx.x * 64, r0 = blockIdx.y * 64;
  int tid = threadIdx.x;
  #pragma unroll
  for (int it = 0; it < 16; ++it) {
    int idx = it * 256 + tid;
    int r = idx >> 6, c = idx & 63;
    tile[r][c] = f2bf(in[(size_t)(r0 + r) * C + c0 + c]);
  }
  __syncthreads();
  #pragma unroll
  for (int it = 0; it < 16; ++it) {
    int idx = it * 256 + tid;
    int r = idx >> 6, c = idx & 63;
    out[(size_t)(c0 + r) * R + r0 + c] = tile[c][r];
  }
}

// ---------------- QKV GEMM: C[4096,3072] = A[4096,1024] * BT[3072,1024]^T + bias ----
__global__ __launch_bounds__(256) void k_gemm_qkv(
    const unsigned short* __restrict__ A,
    const unsigned short* __restrict__ BT,
    const float* __restrict__ bias,
    float* __restrict__ outp,          // d_out base; present at +A_SIZE
    unsigned short* __restrict__ q_ws,
    unsigned short* __restrict__ k_ws,
    unsigned short* __restrict__ vT_ws) {
  const int K = 1024;
  __shared__ unsigned short Asm[128 * 32];
  __shared__ unsigned short Bsm[128 * 32];
  int tid = threadIdx.x;
  int lane = tid & 63, w = tid >> 6;
  int g = lane >> 4, qi = lane & 15;
  int wr = w >> 1, wc = w & 1;
  int bm = blockIdx.x & 31, bn = blockIdx.x >> 5;
  const unsigned short* Ag = A + (size_t)bm * 128 * K;
  const unsigned short* Bg = BT + (size_t)bn * 128 * K;
  f32x4 acc[4][4] = {};
  for (int kt = 0; kt < K; kt += 32) {
    #pragma unroll
    for (int i = 0; i < 2; ++i) {
      int j = i * 256 + tid;
      async16(Ag + (size_t)(j >> 2) * K + kt + (j & 3) * 8,
              (char*)Asm + (i * 256 + w * 64) * 16);
      async16(Bg + (size_t)(j >> 2) * K + kt + (j & 3) * 8,
              (char*)Bsm + (i * 256 + w * 64) * 16);
    }
    __syncthreads();
    short8 af[4], bf[4];
    #pragma unroll
    for (int mi = 0; mi < 4; ++mi)
      af[mi] = *(const short8*)&Asm[(wr * 64 + mi * 16 + qi) * 32 + g * 8];
    #pragma unroll
    for (int ni = 0; ni < 4; ++ni)
      bf[ni] = *(const short8*)&Bsm[(wc * 64 + ni * 16 + qi) * 32 + g * 8];
    #pragma unroll
    for (int mi = 0; mi < 4; ++mi)
      #pragma unroll
      for (int ni = 0; ni < 4; ++ni)
        acc[mi][ni] = __builtin_amdgcn_mfma_f32_16x16x32_bf16(af[mi], bf[ni], acc[mi][ni], 0, 0, 0);
    __syncthreads();
  }
  // Epilogue: scatter to q/k (bf16, [B,H,S,d]), v transposed ([B,H,d,S]), present (fp32).
  int m_base = bm * 128 + wr * 64;
  int n_base = bn * 128 + wc * 64;
  #pragma unroll
  for (int ni = 0; ni < 4; ++ni) {
    int n = n_base + ni * 16 + qi;
    float bv = bias[n];
    int which = n >> 10;
    int h = (n & 1023) >> 6, d = n & 63;
    #pragma unroll
    for (int mi = 0; mi < 4; ++mi) {
      #pragma unroll
      for (int r = 0; r < 4; ++r) {
        int m = m_base + mi * 16 + g * 4 + r;
        float val = acc[mi][ni][r] + bv;
        int b = m >> 11, s = m & 2047;
        if (which == 0) {
          q_ws[(((size_t)(b * 16 + h)) * SEQ + s) * 64 + d] = f2bf(val);
        } else if (which == 1) {
          outp[A_SIZE + (((size_t)(b * 32 + h)) * SEQ + s) * 64 + d] = val;      // present[b][0][h]
          k_ws[(((size_t)(b * 16 + h)) * SEQ + s) * 64 + d] = f2bf(val);
        } else {
          outp[A_SIZE + (((size_t)(b * 32 + 16 + h)) * SEQ + s) * 64 + d] = val; // present[b][1][h]
          vT_ws[(((size_t)(b * 16 + h)) * 64 + d) * SEQ + s] = f2bf(val);        // V^T
        }
      }
    }
  }
}

// ---------------- proj GEMM: out[4096,1024] = A[4096,1024] * BT[1024,1024]^T + bias ----
__global__ __launch_bounds__(256) void k_gemm_proj(
    const unsigned short* __restrict__ A,
    const unsigned short* __restrict__ BT,
    const float* __restrict__ bias,
    float* __restrict__ outp) {
  const int K = 1024;
  __shared__ unsigned short Asm[128 * 32];
  __shared__ unsigned short Bsm[128 * 32];
  int tid = threadIdx.x;
  int lane = tid & 63, w = tid >> 6;
  int g = lane >> 4, qi = lane & 15;
  int wr = w >> 1, wc = w & 1;
  int bm = blockIdx.x & 31, bn = blockIdx.x >> 5;
  const unsigned short* Ag = A + (size_t)bm * 128 * K;
  const unsigned short* Bg = BT + (size_t)bn * 128 * K;
  f32x4 acc[4][4] = {};
  for (int kt = 0; kt < K; kt += 32) {
    #pragma unroll
    for (int i = 0; i < 2; ++i) {
      int j = i * 256 + tid;
      async16(Ag + (size_t)(j >> 2) * K + kt + (j & 3) * 8,
              (char*)Asm + (i * 256 + w * 64) * 16);
      async16(Bg + (size_t)(j >> 2) * K + kt + (j & 3) * 8,
              (char*)Bsm + (i * 256 + w * 64) * 16);
    }
    __syncthreads();
    short8 af[4], bf[4];
    #pragma unroll
    for (int mi = 0; mi < 4; ++mi)
      af[mi] = *(const short8*)&Asm[(wr * 64 + mi * 16 + qi) * 32 + g * 8];
    #pragma unroll
    for (int ni = 0; ni < 4; ++ni)
      bf[ni] = *(const short8*)&Bsm[(wc * 64 + ni * 16 + qi) * 32 + g * 8];
    #pragma unroll
    for (int mi = 0; mi < 4; ++mi)
      #pragma unroll
      for (int ni = 0; ni < 4; ++ni)
        acc[mi][ni] = __builtin_amdgcn_mfma_f32_16x16x32_bf16(af[mi], bf[ni], acc[mi][ni], 0, 0, 0);
    __syncthreads();
  }
  int m_base = bm * 128 + wr * 64;
  int n_base = bn * 128 + wc * 64;
  #pragma unroll
  for (int ni = 0; ni < 4; ++ni) {
    int n = n_base + ni * 16 + qi;
    float bv = bias[n];
    #pragma unroll
    for (int mi = 0; mi < 4; ++mi)
      #pragma unroll
      for (int r = 0; r < 4; ++r) {
        int m = m_base + mi * 16 + g * 4 + r;
        outp[(size_t)m * 1024 + n] = acc[mi][ni][r] + bv;
      }
  }
}

// ---------------- flash attention (causal), barrier-free ----------------
// 64-key unmasked body + 32-key masked tail, defer-max, exp2 softmax,
// truncating bf16 pack via v_perm. O^T = mfma(V^T, P^T): alpha/l per-lane.
#define CSC 0.18033688f   /* 0.125 * log2(e) */
__global__ __launch_bounds__(256) void k_attn(
    const unsigned short* __restrict__ q_ws,
    const unsigned short* __restrict__ k_ws,
    const unsigned short* __restrict__ vT_ws,
    unsigned short* __restrict__ a_out) {
  __shared__ unsigned short P[4][16 * 72];   // per-wave P [q=16][k=64], stride 72 (16B-aligned rows)
  const int nqb = SEQ / 64;   // 32
  int qidx = blockIdx.x / 32;
  int bh = blockIdx.x % 32;
  int q0 = (nqb - 1 - qidx) * 64;           // heaviest causal blocks launch first
  int tid = threadIdx.x, lane = tid & 63, w = tid >> 6;
  int g = lane >> 4, qi = lane & 15;
  int qw = q0 + w * 16;
  int qrow = qw + qi;
  const unsigned short* Qb = q_ws + (size_t)bh * SEQ * 64;
  const unsigned short* Kb = k_ws + (size_t)bh * SEQ * 64;
  const unsigned short* Vb = vT_ws + (size_t)bh * 64 * SEQ;
  unsigned short* Pw = &P[w][0];

  short8 qf0 = *(const short8*)&Qb[(size_t)qrow * 64 + g * 8];
  short8 qf1 = *(const short8*)&Qb[(size_t)qrow * 64 + g * 8 + 32];

  f32x4 oacc[4] = {};
  float m2 = -1.0e30f, l_run = 0.f;
  f32x4 z = {};

  // ---- unmasked 64-key body ----
  int nfull = qw >> 6;
  for (int kb = 0; kb < nfull; ++kb) {
    int k0 = kb * 64;
    short8 kf[4][2];
    #pragma unroll
    for (int st = 0; st < 4; ++st) {
      kf[st][0] = *(const short8*)&Kb[(size_t)(k0 + st * 16 + qi) * 64 + g * 8];
      kf[st][1] = *(const short8*)&Kb[(size_t)(k0 + st * 16 + qi) * 64 + g * 8 + 32];
    }
    f32x4 sa[4];
    #pragma unroll
    for (int st = 0; st < 4; ++st) {
      sa[st] = __builtin_amdgcn_mfma_f32_16x16x32_bf16(kf[st][0], qf0, z, 0, 0, 0);
      sa[st] = __builtin_amdgcn_mfma_f32_16x16x32_bf16(kf[st][1], qf1, sa[st], 0, 0, 0);
    }
    float t[16];
    float tm = -1.0e30f;
    #pragma unroll
    for (int st = 0; st < 4; ++st)
      #pragma unroll
      for (int r = 0; r < 4; ++r) {
        float v = sa[st][r] * CSC;
        t[st * 4 + r] = v;
        tm = fmaxf(tm, v);
      }
    tm = fmaxf(tm, __shfl_xor(tm, 16, 64));
    tm = fmaxf(tm, __shfl_xor(tm, 32, 64));
    if (!__all(tm - m2 <= 4.0f)) {          // defer-max: rescale only when needed
      float mn = fmaxf(m2, tm);
      float alpha = exp2f(m2 - mn);
      l_run *= alpha;
      #pragma unroll
      for (int dt = 0; dt < 4; ++dt)
        #pragma unroll
        for (int r = 0; r < 4; ++r) oacc[dt][r] *= alpha;
      m2 = mn;
    }
    float ps = 0.f;
    uint32_t pk[8];
    #pragma unroll
    for (int i = 0; i < 8; ++i) {
      float p0 = exp2f(t[2 * i] - m2);
      float p1 = exp2f(t[2 * i + 1] - m2);
      ps += p0 + p1;
      pk[i] = pack_bf2(p0, p1);
    }
    ps += __shfl_xor(ps, 16, 64);
    ps += __shfl_xor(ps, 32, 64);
    l_run += ps;
    #pragma unroll
    for (int st = 0; st < 4; ++st) {
      *(uint32_t*)&Pw[qi * 72 + st * 16 + g * 4] = pk[st * 2];
      *(uint32_t*)&Pw[qi * 72 + st * 16 + g * 4 + 2] = pk[st * 2 + 1];
    }
    short8 pB0 = *(const short8*)&Pw[qi * 72 + g * 8];
    short8 pB1 = *(const short8*)&Pw[qi * 72 + 32 + g * 8];
    #pragma unroll
    for (int dt = 0; dt < 4; ++dt) {
      short8 vf0 = *(const short8*)&Vb[(size_t)(dt * 16 + qi) * SEQ + k0 + g * 8];
      short8 vf1 = *(const short8*)&Vb[(size_t)(dt * 16 + qi) * SEQ + k0 + 32 + g * 8];
      oacc[dt] = __builtin_amdgcn_mfma_f32_16x16x32_bf16(vf0, pB0, oacc[dt], 0, 0, 0);
      oacc[dt] = __builtin_amdgcn_mfma_f32_16x16x32_bf16(vf1, pB1, oacc[dt], 0, 0, 0);
    }
  }

  // ---- masked 32-key tail (1 or 2 iterations) ----
  int k0t = qw & ~63;
  int ntail = ((qw & 63) + 16 + 31) >> 5;
  for (int tt = 0; tt < ntail; ++tt) {
    int k0 = k0t + tt * 32;
    short8 kf00 = *(const short8*)&Kb[(size_t)(k0 + qi) * 64 + g * 8];
    short8 kf01 = *(const short8*)&Kb[(size_t)(k0 + qi) * 64 + g * 8 + 32];
    short8 kf10 = *(const short8*)&Kb[(size_t)(k0 + 16 + qi) * 64 + g * 8];
    short8 kf11 = *(const short8*)&Kb[(size_t)(k0 + 16 + qi) * 64 + g * 8 + 32];
    f32x4 s0 = __builtin_amdgcn_mfma_f32_16x16x32_bf16(kf00, qf0, z, 0, 0, 0);
    s0 = __builtin_amdgcn_mfma_f32_16x16x32_bf16(kf01, qf1, s0, 0, 0, 0);
    f32x4 s1 = __builtin_amdgcn_mfma_f32_16x16x32_bf16(kf10, qf0, z, 0, 0, 0);
    s1 = __builtin_amdgcn_mfma_f32_16x16x32_bf16(kf11, qf1, s1, 0, 0, 0);
    float t[8];
    float tm = -1.0e30f;
    #pragma unroll
    for (int r = 0; r < 4; ++r) {
      int key0 = k0 + g * 4 + r;
      float v0 = (key0 <= qrow) ? s0[r] * CSC : -1.0e30f;
      float v1 = (key0 + 16 <= qrow) ? s1[r] * CSC : -1.0e30f;
      t[r] = v0; t[4 + r] = v1;
      tm = fmaxf(tm, fmaxf(v0, v1));
    }
    tm = fmaxf(tm, __shfl_xor(tm, 16, 64));
    tm = fmaxf(tm, __shfl_xor(tm, 32, 64));
    if (!__all(tm - m2 <= 4.0f)) {
      float mn = fmaxf(m2, tm);
      float alpha = exp2f(m2 - mn);
      l_run *= alpha;
      #pragma unroll
      for (int dt = 0; dt < 4; ++dt)
        #pragma unroll
        for (int r = 0; r < 4; ++r) oacc[dt][r] *= alpha;
      m2 = mn;
    }
    float ps = 0.f;
    uint32_t pk[4];
    #pragma unroll
    for (int i = 0; i < 4; ++i) {
      float p0 = exp2f(t[2 * i] - m2);
      float p1 = exp2f(t[2 * i + 1] - m2);
      ps += p0 + p1;
      pk[i] = pack_bf2(p0, p1);
    }
    ps += __shfl_xor(ps, 16, 64);
    ps += __shfl_xor(ps, 32, 64);
    l_run += ps;
    #pragma unroll
    for (int st = 0; st < 2; ++st) {
      *(uint32_t*)&Pw[qi * 72 + st * 16 + g * 4] = pk[st * 2];
      *(uint32_t*)&Pw[qi * 72 + st * 16 + g * 4 + 2] = pk[st * 2 + 1];
    }
    short8 pB = *(const short8*)&Pw[qi * 72 + g * 8];
    #pragma unroll
    for (int dt = 0; dt < 4; ++dt) {
      short8 vf = *(const short8*)&Vb[(size_t)(dt * 16 + qi) * SEQ + k0 + g * 8];
      oacc[dt] = __builtin_amdgcn_mfma_f32_16x16x32_bf16(vf, pB, oacc[dt], 0, 0, 0);
    }
  }

  float inv = 1.0f / l_run;   // l_run is this lane's own q-row denom
  int b = bh >> 4, h = bh & 15;
  size_t rowbase = ((size_t)(b * SEQ + qw + qi)) * 1024 + h * 64;
  #pragma unroll
  for (int dt = 0; dt < 4; ++dt) {
    ushort4 o;
    o.x = f2bf(oacc[dt][0] * inv);
    o.y = f2bf(oacc[dt][1] * inv);
    o.z = f2bf(oacc[dt][2] * inv);
    o.w = f2bf(oacc[dt][3] * inv);
    *(ushort4*)&a_out[rowbase + dt * 16 + g * 4] = o;
  }
}

// ---------------- launch ----------------
extern "C" void kernel_launch(void* const* d_in, const int* in_sizes, int n_in,
                              void* d_out, int out_size, void* d_ws, size_t ws_size,
                              hipStream_t stream) {
  const float* x      = (const float*)d_in[0];
  const float* w_attn = (const float*)d_in[1];
  const float* b_attn = (const float*)d_in[2];
  const float* w_proj = (const float*)d_in[3];
  const float* b_proj = (const float*)d_in[4];
  float* out = (float*)d_out;
  char* ws = (char*)d_ws;
  // ws layout (48 MB total)
  unsigned short* x_bf  = (unsigned short*)(ws);               //  8 MB
  unsigned short* waT   = (unsigned short*)(ws + 8388608);     //  6 MB
  unsigned short* wpT   = (unsigned short*)(ws + 14680064);    //  2 MB
  unsigned short* q_ws  = (unsigned short*)(ws + 16777216);    //  8 MB
  unsigned short* k_ws  = (unsigned short*)(ws + 25165824);    //  8 MB
  unsigned short* vT_ws = (unsigned short*)(ws + 33554432);    //  8 MB
  unsigned short* a_ws  = (unsigned short*)(ws + 41943040);    //  8 MB

  hipLaunchKernelGGL(k_cvt, dim3(4096), dim3(256), 0, stream, x, x_bf, 4194304 / 4);
  hipLaunchKernelGGL(k_tcvt, dim3(48, 16), dim3(256), 0, stream, w_attn, waT, 1024, 3072);
  hipLaunchKernelGGL(k_tcvt, dim3(16, 16), dim3(256), 0, stream, w_proj, wpT, 1024, 1024);
  hipLaunchKernelGGL(k_gemm_qkv, dim3(768), dim3(256), 0, stream,
                     x_bf, waT, b_attn, out, q_ws, k_ws, vT_ws);
  hipLaunchKernelGGL(k_attn, dim3(1024), dim3(256), 0, stream, q_ws, k_ws, vT_ws, a_ws);
  hipLaunchKernelGGL(k_gemm_proj, dim3(256), dim3(256), 0, stream, a_ws, wpT, b_proj, out);
}

// Round 4
// 195.968 us; speedup vs baseline: 1.1314x; 1.1314x over previous
//
#include <hip/hip_runtime.h>
#include <stdint.h>

// Problem dims (fixed): B=2, S=2048, D=1024, H=16, d_head=64
#define SEQ 2048
#define A_SIZE 4194304   // 2*2048*1024 floats (output 'a'), present follows

typedef short short8 __attribute__((ext_vector_type(8)));
typedef float f32x4 __attribute__((ext_vector_type(4)));

#define AS1 __attribute__((address_space(1)))
#define AS3 __attribute__((address_space(3)))

static __device__ __forceinline__ void async16(const void* g, void* l) {
  __builtin_amdgcn_global_load_lds((const AS1 uint32_t*)g, (AS3 uint32_t*)l, 16, 0, 0);
}

static __device__ __forceinline__ unsigned short f2bf(float f) {
  union { float f; uint32_t u; } v; v.f = f;
  uint32_t u = v.u;
  return (unsigned short)((u + 0x7FFFu + ((u >> 16) & 1u)) >> 16);
}

static __device__ __forceinline__ uint32_t fbits(float f) {
  union { float f; uint32_t u; } v; v.f = f;
  return v.u;
}

// pack two floats to two truncated bf16 in one u32: low=p0, high=p1
static __device__ __forceinline__ uint32_t pack_bf2(float p0, float p1) {
  return __builtin_amdgcn_perm(fbits(p1), fbits(p0), 0x07060302u);
}

// ---------------- convert x -> bf16 (straight) ----------------
__global__ void k_cvt(const float* __restrict__ in, unsigned short* __restrict__ out, int n4) {
  int i = blockIdx.x * blockDim.x + threadIdx.x;
  if (i >= n4) return;
  float4 f = ((const float4*)in)[i];
  ushort4 o;
  o.x = f2bf(f.x); o.y = f2bf(f.y); o.z = f2bf(f.z); o.w = f2bf(f.w);
  ((ushort4*)out)[i] = o;
}

// ------- convert + transpose: in [R][C] f32 -> out [C][R] bf16 -------
__global__ void k_tcvt(const float* __restrict__ in, unsigned short* __restrict__ out,
                       int R, int C) {
  __shared__ unsigned short tile[64][65];
  int c0 = blockIdx.x * 64, r0 = blockIdx.y * 64;
  int tid = threadIdx.x;
  #pragma unroll
  for (int it = 0; it < 16; ++it) {
    int idx = it * 256 + tid;
    int r = idx >> 6, c = idx & 63;
    tile[r][c] = f2bf(in[(size_t)(r0 + r) * C + c0 + c]);
  }
  __syncthreads();
  #pragma unroll
  for (int it = 0; it < 16; ++it) {
    int idx = it * 256 + tid;
    int r = idx >> 6, c = idx & 63;
    out[(size_t)(c0 + r) * R + r0 + c] = tile[c][r];
  }
}

// ---------------- QKV GEMM: C[4096,3072] = A[4096,1024] * BT[3072,1024]^T + bias ----
__global__ __launch_bounds__(256) void k_gemm_qkv(
    const unsigned short* __restrict__ A,
    const unsigned short* __restrict__ BT,
    const float* __restrict__ bias,
    float* __restrict__ outp,          // d_out base; present at +A_SIZE
    unsigned short* __restrict__ q_ws,
    unsigned short* __restrict__ k_ws,
    unsigned short* __restrict__ vT_ws) {
  const int K = 1024;
  __shared__ unsigned short Asm[128 * 32];
  __shared__ unsigned short Bsm[128 * 32];
  int tid = threadIdx.x;
  int lane = tid & 63, w = tid >> 6;
  int g = lane >> 4, qi = lane & 15;
  int wr = w >> 1, wc = w & 1;
  int bm = blockIdx.x & 31, bn = blockIdx.x >> 5;
  const unsigned short* Ag = A + (size_t)bm * 128 * K;
  const unsigned short* Bg = BT + (size_t)bn * 128 * K;
  f32x4 acc[4][4] = {};
  for (int kt = 0; kt < K; kt += 32) {
    #pragma unroll
    for (int i = 0; i < 2; ++i) {
      int j = i * 256 + tid;
      async16(Ag + (size_t)(j >> 2) * K + kt + (j & 3) * 8,
              (char*)Asm + (i * 256 + w * 64) * 16);
      async16(Bg + (size_t)(j >> 2) * K + kt + (j & 3) * 8,
              (char*)Bsm + (i * 256 + w * 64) * 16);
    }
    __syncthreads();
    short8 af[4], bf[4];
    #pragma unroll
    for (int mi = 0; mi < 4; ++mi)
      af[mi] = *(const short8*)&Asm[(wr * 64 + mi * 16 + qi) * 32 + g * 8];
    #pragma unroll
    for (int ni = 0; ni < 4; ++ni)
      bf[ni] = *(const short8*)&Bsm[(wc * 64 + ni * 16 + qi) * 32 + g * 8];
    #pragma unroll
    for (int mi = 0; mi < 4; ++mi)
      #pragma unroll
      for (int ni = 0; ni < 4; ++ni)
        acc[mi][ni] = __builtin_amdgcn_mfma_f32_16x16x32_bf16(af[mi], bf[ni], acc[mi][ni], 0, 0, 0);
    __syncthreads();
  }
  // Epilogue: scatter to q/k (bf16, [B,H,S,d]), v transposed ([B,H,d,S]), present (fp32).
  int m_base = bm * 128 + wr * 64;
  int n_base = bn * 128 + wc * 64;
  #pragma unroll
  for (int ni = 0; ni < 4; ++ni) {
    int n = n_base + ni * 16 + qi;
    float bv = bias[n];
    int which = n >> 10;
    int h = (n & 1023) >> 6, d = n & 63;
    #pragma unroll
    for (int mi = 0; mi < 4; ++mi) {
      #pragma unroll
      for (int r = 0; r < 4; ++r) {
        int m = m_base + mi * 16 + g * 4 + r;
        float val = acc[mi][ni][r] + bv;
        int b = m >> 11, s = m & 2047;
        if (which == 0) {
          q_ws[(((size_t)(b * 16 + h)) * SEQ + s) * 64 + d] = f2bf(val);
        } else if (which == 1) {
          outp[A_SIZE + (((size_t)(b * 32 + h)) * SEQ + s) * 64 + d] = val;      // present[b][0][h]
          k_ws[(((size_t)(b * 16 + h)) * SEQ + s) * 64 + d] = f2bf(val);
        } else {
          outp[A_SIZE + (((size_t)(b * 32 + 16 + h)) * SEQ + s) * 64 + d] = val; // present[b][1][h]
          vT_ws[(((size_t)(b * 16 + h)) * 64 + d) * SEQ + s] = f2bf(val);        // V^T
        }
      }
    }
  }
}

// ---------------- proj GEMM: out[4096,1024] = A[4096,1024] * BT[1024,1024]^T + bias ----
__global__ __launch_bounds__(256) void k_gemm_proj(
    const unsigned short* __restrict__ A,
    const unsigned short* __restrict__ BT,
    const float* __restrict__ bias,
    float* __restrict__ outp) {
  const int K = 1024;
  __shared__ unsigned short Asm[128 * 32];
  __shared__ unsigned short Bsm[128 * 32];
  int tid = threadIdx.x;
  int lane = tid & 63, w = tid >> 6;
  int g = lane >> 4, qi = lane & 15;
  int wr = w >> 1, wc = w & 1;
  int bm = blockIdx.x & 31, bn = blockIdx.x >> 5;
  const unsigned short* Ag = A + (size_t)bm * 128 * K;
  const unsigned short* Bg = BT + (size_t)bn * 128 * K;
  f32x4 acc[4][4] = {};
  for (int kt = 0; kt < K; kt += 32) {
    #pragma unroll
    for (int i = 0; i < 2; ++i) {
      int j = i * 256 + tid;
      async16(Ag + (size_t)(j >> 2) * K + kt + (j & 3) * 8,
              (char*)Asm + (i * 256 + w * 64) * 16);
      async16(Bg + (size_t)(j >> 2) * K + kt + (j & 3) * 8,
              (char*)Bsm + (i * 256 + w * 64) * 16);
    }
    __syncthreads();
    short8 af[4], bf[4];
    #pragma unroll
    for (int mi = 0; mi < 4; ++mi)
      af[mi] = *(const short8*)&Asm[(wr * 64 + mi * 16 + qi) * 32 + g * 8];
    #pragma unroll
    for (int ni = 0; ni < 4; ++ni)
      bf[ni] = *(const short8*)&Bsm[(wc * 64 + ni * 16 + qi) * 32 + g * 8];
    #pragma unroll
    for (int mi = 0; mi < 4; ++mi)
      #pragma unroll
      for (int ni = 0; ni < 4; ++ni)
        acc[mi][ni] = __builtin_amdgcn_mfma_f32_16x16x32_bf16(af[mi], bf[ni], acc[mi][ni], 0, 0, 0);
    __syncthreads();
  }
  int m_base = bm * 128 + wr * 64;
  int n_base = bn * 128 + wc * 64;
  #pragma unroll
  for (int ni = 0; ni < 4; ++ni) {
    int n = n_base + ni * 16 + qi;
    float bv = bias[n];
    #pragma unroll
    for (int mi = 0; mi < 4; ++mi)
      #pragma unroll
      for (int r = 0; r < 4; ++r) {
        int m = m_base + mi * 16 + g * 4 + r;
        outp[(size_t)m * 1024 + n] = acc[mi][ni][r] + bv;
      }
  }
}

// ---------------- flash attention (causal), barrier-free, load-balanced ----------------
// 512 blocks x 8 waves: waves 0-3 -> heavy q-tile (31-p), waves 4-7 -> light q-tile p.
// Every block has equal total work -> occupancy stays flat (no drain tail).
// Steady-state softmax has NO cross-lane ops: defer-max check uses per-lane
// partial max under __all (sufficient bound); l accumulates per-lane, reduced once at end.
#define CSC 0.18033688f   /* 0.125 * log2(e) */
__global__ __launch_bounds__(512) void k_attn(
    const unsigned short* __restrict__ q_ws,
    const unsigned short* __restrict__ k_ws,
    const unsigned short* __restrict__ vT_ws,
    unsigned short* __restrict__ a_out) {
  __shared__ unsigned short P[8][16 * 72];   // per-wave P [q=16][k<=64], stride 72
  int pairidx = blockIdx.x >> 5;            // 0..15
  int bh = blockIdx.x & 31;
  int tid = threadIdx.x, lane = tid & 63, w = tid >> 6;
  int g = lane >> 4, qi = lane & 15;
  int tilesel = w >> 2, wl = w & 3;
  int q0 = (tilesel ? pairidx : (31 - pairidx)) * 64;
  int qw = q0 + wl * 16;
  int qrow = qw + qi;
  const unsigned short* Qb = q_ws + (size_t)bh * SEQ * 64;
  const unsigned short* Kb = k_ws + (size_t)bh * SEQ * 64;
  const unsigned short* Vb = vT_ws + (size_t)bh * 64 * SEQ;
  unsigned short* Pw = &P[w][0];

  short8 qf0 = *(const short8*)&Qb[(size_t)qrow * 64 + g * 8];
  short8 qf1 = *(const short8*)&Qb[(size_t)qrow * 64 + g * 8 + 32];

  f32x4 oacc[4] = {};
  float m2 = -1.0e30f, l_run = 0.f;   // l_run: per-lane partial sum
  f32x4 z = {};

  // ---- unmasked 64-key body ----
  int nfull = qw >> 6;
  for (int kb = 0; kb < nfull; ++kb) {
    int k0 = kb * 64;
    short8 kf[4][2];
    #pragma unroll
    for (int st = 0; st < 4; ++st) {
      kf[st][0] = *(const short8*)&Kb[(size_t)(k0 + st * 16 + qi) * 64 + g * 8];
      kf[st][1] = *(const short8*)&Kb[(size_t)(k0 + st * 16 + qi) * 64 + g * 8 + 32];
    }
    f32x4 sa[4];
    #pragma unroll
    for (int st = 0; st < 4; ++st) {
      sa[st] = __builtin_amdgcn_mfma_f32_16x16x32_bf16(kf[st][0], qf0, z, 0, 0, 0);
      sa[st] = __builtin_amdgcn_mfma_f32_16x16x32_bf16(kf[st][1], qf1, sa[st], 0, 0, 0);
    }
    float t[16];
    float tm = -1.0e30f;
    #pragma unroll
    for (int st = 0; st < 4; ++st)
      #pragma unroll
      for (int r = 0; r < 4; ++r) {
        float v = sa[st][r] * CSC;
        t[st * 4 + r] = v;
        tm = fmaxf(tm, v);
      }
    // defer-max: per-lane partial bound; rescale path (rare) does the row reduce
    if (!__all(tm - m2 <= 4.0f)) {
      tm = fmaxf(tm, __shfl_xor(tm, 16, 64));
      tm = fmaxf(tm, __shfl_xor(tm, 32, 64));
      float mn = fmaxf(m2, tm);
      float alpha = exp2f(m2 - mn);
      l_run *= alpha;
      #pragma unroll
      for (int dt = 0; dt < 4; ++dt)
        #pragma unroll
        for (int r = 0; r < 4; ++r) oacc[dt][r] *= alpha;
      m2 = mn;
    }
    float ps = 0.f;
    uint32_t pk[8];
    #pragma unroll
    for (int i = 0; i < 8; ++i) {
      float p0 = exp2f(t[2 * i] - m2);
      float p1 = exp2f(t[2 * i + 1] - m2);
      ps += p0 + p1;
      pk[i] = pack_bf2(p0, p1);
    }
    l_run += ps;
    #pragma unroll
    for (int st = 0; st < 4; ++st) {
      *(uint32_t*)&Pw[qi * 72 + st * 16 + g * 4] = pk[st * 2];
      *(uint32_t*)&Pw[qi * 72 + st * 16 + g * 4 + 2] = pk[st * 2 + 1];
    }
    short8 pB0 = *(const short8*)&Pw[qi * 72 + g * 8];
    short8 pB1 = *(const short8*)&Pw[qi * 72 + 32 + g * 8];
    #pragma unroll
    for (int dt = 0; dt < 4; ++dt) {
      short8 vf0 = *(const short8*)&Vb[(size_t)(dt * 16 + qi) * SEQ + k0 + g * 8];
      short8 vf1 = *(const short8*)&Vb[(size_t)(dt * 16 + qi) * SEQ + k0 + 32 + g * 8];
      oacc[dt] = __builtin_amdgcn_mfma_f32_16x16x32_bf16(vf0, pB0, oacc[dt], 0, 0, 0);
      oacc[dt] = __builtin_amdgcn_mfma_f32_16x16x32_bf16(vf1, pB1, oacc[dt], 0, 0, 0);
    }
  }

  // ---- masked 32-key tail (1 or 2 iterations) ----
  int k0t = qw & ~63;
  int ntail = ((qw & 63) + 16 + 31) >> 5;
  for (int tt = 0; tt < ntail; ++tt) {
    int k0 = k0t + tt * 32;
    short8 kf00 = *(const short8*)&Kb[(size_t)(k0 + qi) * 64 + g * 8];
    short8 kf01 = *(const short8*)&Kb[(size_t)(k0 + qi) * 64 + g * 8 + 32];
    short8 kf10 = *(const short8*)&Kb[(size_t)(k0 + 16 + qi) * 64 + g * 8];
    short8 kf11 = *(const short8*)&Kb[(size_t)(k0 + 16 + qi) * 64 + g * 8 + 32];
    f32x4 s0 = __builtin_amdgcn_mfma_f32_16x16x32_bf16(kf00, qf0, z, 0, 0, 0);
    s0 = __builtin_amdgcn_mfma_f32_16x16x32_bf16(kf01, qf1, s0, 0, 0, 0);
    f32x4 s1 = __builtin_amdgcn_mfma_f32_16x16x32_bf16(kf10, qf0, z, 0, 0, 0);
    s1 = __builtin_amdgcn_mfma_f32_16x16x32_bf16(kf11, qf1, s1, 0, 0, 0);
    float t[8];
    float tm = -1.0e30f;
    #pragma unroll
    for (int r = 0; r < 4; ++r) {
      int key0 = k0 + g * 4 + r;
      float v0 = (key0 <= qrow) ? s0[r] * CSC : -1.0e30f;
      float v1 = (key0 + 16 <= qrow) ? s1[r] * CSC : -1.0e30f;
      t[r] = v0; t[4 + r] = v1;
      tm = fmaxf(tm, fmaxf(v0, v1));
    }
    if (!__all(tm - m2 <= 4.0f)) {
      tm = fmaxf(tm, __shfl_xor(tm, 16, 64));
      tm = fmaxf(tm, __shfl_xor(tm, 32, 64));
      float mn = fmaxf(m2, tm);
      float alpha = exp2f(m2 - mn);
      l_run *= alpha;
      #pragma unroll
      for (int dt = 0; dt < 4; ++dt)
        #pragma unroll
        for (int r = 0; r < 4; ++r) oacc[dt][r] *= alpha;
      m2 = mn;
    }
    float ps = 0.f;
    uint32_t pk[4];
    #pragma unroll
    for (int i = 0; i < 4; ++i) {
      float p0 = exp2f(t[2 * i] - m2);
      float p1 = exp2f(t[2 * i + 1] - m2);
      ps += p0 + p1;
      pk[i] = pack_bf2(p0, p1);
    }
    l_run += ps;
    #pragma unroll
    for (int st = 0; st < 2; ++st) {
      *(uint32_t*)&Pw[qi * 72 + st * 16 + g * 4] = pk[st * 2];
      *(uint32_t*)&Pw[qi * 72 + st * 16 + g * 4 + 2] = pk[st * 2 + 1];
    }
    short8 pB = *(const short8*)&Pw[qi * 72 + g * 8];
    #pragma unroll
    for (int dt = 0; dt < 4; ++dt) {
      short8 vf = *(const short8*)&Vb[(size_t)(dt * 16 + qi) * SEQ + k0 + g * 8];
      oacc[dt] = __builtin_amdgcn_mfma_f32_16x16x32_bf16(vf, pB, oacc[dt], 0, 0, 0);
    }
  }

  // one-time l reduce across the 4 lane-groups of each q-row
  l_run += __shfl_xor(l_run, 16, 64);
  l_run += __shfl_xor(l_run, 32, 64);
  float inv = 1.0f / l_run;
  int b = bh >> 4, h = bh & 15;
  size_t rowbase = ((size_t)(b * SEQ + qw + qi)) * 1024 + h * 64;
  #pragma unroll
  for (int dt = 0; dt < 4; ++dt) {
    ushort4 o;
    o.x = f2bf(oacc[dt][0] * inv);
    o.y = f2bf(oacc[dt][1] * inv);
    o.z = f2bf(oacc[dt][2] * inv);
    o.w = f2bf(oacc[dt][3] * inv);
    *(ushort4*)&a_out[rowbase + dt * 16 + g * 4] = o;
  }
}

// ---------------- launch ----------------
extern "C" void kernel_launch(void* const* d_in, const int* in_sizes, int n_in,
                              void* d_out, int out_size, void* d_ws, size_t ws_size,
                              hipStream_t stream) {
  const float* x      = (const float*)d_in[0];
  const float* w_attn = (const float*)d_in[1];
  const float* b_attn = (const float*)d_in[2];
  const float* w_proj = (const float*)d_in[3];
  const float* b_proj = (const float*)d_in[4];
  float* out = (float*)d_out;
  char* ws = (char*)d_ws;
  // ws layout (48 MB total)
  unsigned short* x_bf  = (unsigned short*)(ws);               //  8 MB
  unsigned short* waT   = (unsigned short*)(ws + 8388608);     //  6 MB
  unsigned short* wpT   = (unsigned short*)(ws + 14680064);    //  2 MB
  unsigned short* q_ws  = (unsigned short*)(ws + 16777216);    //  8 MB
  unsigned short* k_ws  = (unsigned short*)(ws + 25165824);    //  8 MB
  unsigned short* vT_ws = (unsigned short*)(ws + 33554432);    //  8 MB
  unsigned short* a_ws  = (unsigned short*)(ws + 41943040);    //  8 MB

  hipLaunchKernelGGL(k_cvt, dim3(4096), dim3(256), 0, stream, x, x_bf, 4194304 / 4);
  hipLaunchKernelGGL(k_tcvt, dim3(48, 16), dim3(256), 0, stream, w_attn, waT, 1024, 3072);
  hipLaunchKernelGGL(k_tcvt, dim3(16, 16), dim3(256), 0, stream, w_proj, wpT, 1024, 1024);
  hipLaunchKernelGGL(k_gemm_qkv, dim3(768), dim3(256), 0, stream,
                     x_bf, waT, b_attn, out, q_ws, k_ws, vT_ws);
  hipLaunchKernelGGL(k_attn, dim3(512), dim3(512), 0, stream, q_ws, k_ws, vT_ws, a_ws);
  hipLaunchKernelGGL(k_gemm_proj, dim3(256), dim3(256), 0, stream, a_ws, wpT, b_proj, out);
}

// Round 5
// 194.790 us; speedup vs baseline: 1.1383x; 1.0060x over previous
//
#include <hip/hip_runtime.h>
#include <stdint.h>

// Problem dims (fixed): B=2, S=2048, D=1024, H=16, d_head=64
#define SEQ 2048
#define A_SIZE 4194304   // 2*2048*1024 floats (output 'a'), present follows

typedef short short8 __attribute__((ext_vector_type(8)));
typedef float f32x4 __attribute__((ext_vector_type(4)));

#define AS1 __attribute__((address_space(1)))
#define AS3 __attribute__((address_space(3)))

static __device__ __forceinline__ void async16(const void* g, void* l) {
  __builtin_amdgcn_global_load_lds((const AS1 uint32_t*)g, (AS3 uint32_t*)l, 16, 0, 0);
}

static __device__ __forceinline__ unsigned short f2bf(float f) {
  union { float f; uint32_t u; } v; v.f = f;
  uint32_t u = v.u;
  return (unsigned short)((u + 0x7FFFu + ((u >> 16) & 1u)) >> 16);
}

static __device__ __forceinline__ uint32_t fbits(float f) {
  union { float f; uint32_t u; } v; v.f = f;
  return v.u;
}

// pack two floats to two truncated bf16 in one u32: low=p0, high=p1
static __device__ __forceinline__ uint32_t pack_bf2(float p0, float p1) {
  return __builtin_amdgcn_perm(fbits(p1), fbits(p0), 0x07060302u);
}

// ---------------- convert x -> bf16 (straight) ----------------
__global__ void k_cvt(const float* __restrict__ in, unsigned short* __restrict__ out, int n4) {
  int i = blockIdx.x * blockDim.x + threadIdx.x;
  if (i >= n4) return;
  float4 f = ((const float4*)in)[i];
  ushort4 o;
  o.x = f2bf(f.x); o.y = f2bf(f.y); o.z = f2bf(f.z); o.w = f2bf(f.w);
  ((ushort4*)out)[i] = o;
}

// ------- convert + transpose: in [R][C] f32 -> out [C][R] bf16 -------
__global__ void k_tcvt(const float* __restrict__ in, unsigned short* __restrict__ out,
                       int R, int C) {
  __shared__ unsigned short tile[64][65];
  int c0 = blockIdx.x * 64, r0 = blockIdx.y * 64;
  int tid = threadIdx.x;
  #pragma unroll
  for (int it = 0; it < 16; ++it) {
    int idx = it * 256 + tid;
    int r = idx >> 6, c = idx & 63;
    tile[r][c] = f2bf(in[(size_t)(r0 + r) * C + c0 + c]);
  }
  __syncthreads();
  #pragma unroll
  for (int it = 0; it < 16; ++it) {
    int idx = it * 256 + tid;
    int r = idx >> 6, c = idx & 63;
    out[(size_t)(c0 + r) * R + r0 + c] = tile[c][r];
  }
}

// ---------------- QKV GEMM: C[4096,3072] = A[4096,1024] * BT[3072,1024]^T + bias ----
__global__ __launch_bounds__(256) void k_gemm_qkv(
    const unsigned short* __restrict__ A,
    const unsigned short* __restrict__ BT,
    const float* __restrict__ bias,
    float* __restrict__ outp,          // d_out base; present at +A_SIZE
    unsigned short* __restrict__ q_ws,
    unsigned short* __restrict__ k_ws,
    unsigned short* __restrict__ vT_ws) {
  const int K = 1024;
  __shared__ unsigned short Asm[128 * 32];
  __shared__ unsigned short Bsm[128 * 32];
  int tid = threadIdx.x;
  int lane = tid & 63, w = tid >> 6;
  int g = lane >> 4, qi = lane & 15;
  int wr = w >> 1, wc = w & 1;
  int bm = blockIdx.x & 31, bn = blockIdx.x >> 5;
  const unsigned short* Ag = A + (size_t)bm * 128 * K;
  const unsigned short* Bg = BT + (size_t)bn * 128 * K;
  f32x4 acc[4][4] = {};
  for (int kt = 0; kt < K; kt += 32) {
    #pragma unroll
    for (int i = 0; i < 2; ++i) {
      int j = i * 256 + tid;
      async16(Ag + (size_t)(j >> 2) * K + kt + (j & 3) * 8,
              (char*)Asm + (i * 256 + w * 64) * 16);
      async16(Bg + (size_t)(j >> 2) * K + kt + (j & 3) * 8,
              (char*)Bsm + (i * 256 + w * 64) * 16);
    }
    __syncthreads();
    short8 af[4], bf[4];
    #pragma unroll
    for (int mi = 0; mi < 4; ++mi)
      af[mi] = *(const short8*)&Asm[(wr * 64 + mi * 16 + qi) * 32 + g * 8];
    #pragma unroll
    for (int ni = 0; ni < 4; ++ni)
      bf[ni] = *(const short8*)&Bsm[(wc * 64 + ni * 16 + qi) * 32 + g * 8];
    #pragma unroll
    for (int mi = 0; mi < 4; ++mi)
      #pragma unroll
      for (int ni = 0; ni < 4; ++ni)
        acc[mi][ni] = __builtin_amdgcn_mfma_f32_16x16x32_bf16(af[mi], bf[ni], acc[mi][ni], 0, 0, 0);
    __syncthreads();
  }
  // Epilogue: scatter to q/k (bf16, [B,H,S,d]), v transposed ([B,H,d,S]), present (fp32).
  int m_base = bm * 128 + wr * 64;
  int n_base = bn * 128 + wc * 64;
  #pragma unroll
  for (int ni = 0; ni < 4; ++ni) {
    int n = n_base + ni * 16 + qi;
    float bv = bias[n];
    int which = n >> 10;
    int h = (n & 1023) >> 6, d = n & 63;
    #pragma unroll
    for (int mi = 0; mi < 4; ++mi) {
      #pragma unroll
      for (int r = 0; r < 4; ++r) {
        int m = m_base + mi * 16 + g * 4 + r;
        float val = acc[mi][ni][r] + bv;
        int b = m >> 11, s = m & 2047;
        if (which == 0) {
          q_ws[(((size_t)(b * 16 + h)) * SEQ + s) * 64 + d] = f2bf(val);
        } else if (which == 1) {
          outp[A_SIZE + (((size_t)(b * 32 + h)) * SEQ + s) * 64 + d] = val;      // present[b][0][h]
          k_ws[(((size_t)(b * 16 + h)) * SEQ + s) * 64 + d] = f2bf(val);
        } else {
          outp[A_SIZE + (((size_t)(b * 32 + 16 + h)) * SEQ + s) * 64 + d] = val; // present[b][1][h]
          vT_ws[(((size_t)(b * 16 + h)) * 64 + d) * SEQ + s] = f2bf(val);        // V^T
        }
      }
    }
  }
}

// ---------------- proj GEMM: out[4096,1024] = A[4096,1024] * BT[1024,1024]^T + bias ----
__global__ __launch_bounds__(256) void k_gemm_proj(
    const unsigned short* __restrict__ A,
    const unsigned short* __restrict__ BT,
    const float* __restrict__ bias,
    float* __restrict__ outp) {
  const int K = 1024;
  __shared__ unsigned short Asm[128 * 32];
  __shared__ unsigned short Bsm[128 * 32];
  int tid = threadIdx.x;
  int lane = tid & 63, w = tid >> 6;
  int g = lane >> 4, qi = lane & 15;
  int wr = w >> 1, wc = w & 1;
  int bm = blockIdx.x & 31, bn = blockIdx.x >> 5;
  const unsigned short* Ag = A + (size_t)bm * 128 * K;
  const unsigned short* Bg = BT + (size_t)bn * 128 * K;
  f32x4 acc[4][4] = {};
  for (int kt = 0; kt < K; kt += 32) {
    #pragma unroll
    for (int i = 0; i < 2; ++i) {
      int j = i * 256 + tid;
      async16(Ag + (size_t)(j >> 2) * K + kt + (j & 3) * 8,
              (char*)Asm + (i * 256 + w * 64) * 16);
      async16(Bg + (size_t)(j >> 2) * K + kt + (j & 3) * 8,
              (char*)Bsm + (i * 256 + w * 64) * 16);
    }
    __syncthreads();
    short8 af[4], bf[4];
    #pragma unroll
    for (int mi = 0; mi < 4; ++mi)
      af[mi] = *(const short8*)&Asm[(wr * 64 + mi * 16 + qi) * 32 + g * 8];
    #pragma unroll
    for (int ni = 0; ni < 4; ++ni)
      bf[ni] = *(const short8*)&Bsm[(wc * 64 + ni * 16 + qi) * 32 + g * 8];
    #pragma unroll
    for (int mi = 0; mi < 4; ++mi)
      #pragma unroll
      for (int ni = 0; ni < 4; ++ni)
        acc[mi][ni] = __builtin_amdgcn_mfma_f32_16x16x32_bf16(af[mi], bf[ni], acc[mi][ni], 0, 0, 0);
    __syncthreads();
  }
  int m_base = bm * 128 + wr * 64;
  int n_base = bn * 128 + wc * 64;
  #pragma unroll
  for (int ni = 0; ni < 4; ++ni) {
    int n = n_base + ni * 16 + qi;
    float bv = bias[n];
    #pragma unroll
    for (int mi = 0; mi < 4; ++mi)
      #pragma unroll
      for (int r = 0; r < 4; ++r) {
        int m = m_base + mi * 16 + g * 4 + r;
        outp[(size_t)m * 1024 + n] = acc[mi][ni][r] + bv;
      }
  }
}

// ---------------- flash attention (causal), barrier-free, load-balanced ----------------
// 512 blocks x 8 waves: waves 0-3 -> heavy q-tile (31-p), waves 4-7 -> light q-tile p.
// __launch_bounds__(512,4): grid caps occupancy at 4 waves/SIMD anyway, so allow
// 128 VGPR -> all 16 global loads per tile stay in flight (MLP) instead of
// being serialized by a 52-VGPR just-in-time schedule.
#define CSC 0.18033688f   /* 0.125 * log2(e) */
__global__ __launch_bounds__(512, 4) void k_attn(
    const unsigned short* __restrict__ q_ws,
    const unsigned short* __restrict__ k_ws,
    const unsigned short* __restrict__ vT_ws,
    unsigned short* __restrict__ a_out) {
  __shared__ unsigned short P[8][2][16 * 72];  // per-wave double-buffered P [q=16][k<=64]
  int pairidx = blockIdx.x >> 5;            // 0..15
  int bh = blockIdx.x & 31;
  int tid = threadIdx.x, lane = tid & 63, w = tid >> 6;
  int g = lane >> 4, qi = lane & 15;
  int tilesel = w >> 2, wl = w & 3;
  int q0 = (tilesel ? pairidx : (31 - pairidx)) * 64;
  int qw = q0 + wl * 16;
  int qrow = qw + qi;
  const unsigned short* Qb = q_ws + (size_t)bh * SEQ * 64;
  const unsigned short* Kb = k_ws + (size_t)bh * SEQ * 64;
  const unsigned short* Vb = vT_ws + (size_t)bh * 64 * SEQ;

  short8 qf0 = *(const short8*)&Qb[(size_t)qrow * 64 + g * 8];
  short8 qf1 = *(const short8*)&Qb[(size_t)qrow * 64 + g * 8 + 32];

  f32x4 oacc[4] = {};
  float m2 = -1.0e30f, l_run = 0.f;   // l_run: per-lane partial sum
  f32x4 z = {};

  // ---- unmasked 64-key body ----
  int nfull = qw >> 6;
  for (int kb = 0; kb < nfull; ++kb) {
    int k0 = kb * 64;
    unsigned short* Pw = &P[w][kb & 1][0];
    // issue ALL 16 global loads (K + V) up front -> one latency wait, full MLP
    short8 kf[4][2];
    #pragma unroll
    for (int st = 0; st < 4; ++st) {
      kf[st][0] = *(const short8*)&Kb[(size_t)(k0 + st * 16 + qi) * 64 + g * 8];
      kf[st][1] = *(const short8*)&Kb[(size_t)(k0 + st * 16 + qi) * 64 + g * 8 + 32];
    }
    short8 vf0[4], vf1[4];
    #pragma unroll
    for (int dt = 0; dt < 4; ++dt) {
      vf0[dt] = *(const short8*)&Vb[(size_t)(dt * 16 + qi) * SEQ + k0 + g * 8];
      vf1[dt] = *(const short8*)&Vb[(size_t)(dt * 16 + qi) * SEQ + k0 + 32 + g * 8];
    }
    f32x4 sa[4];
    #pragma unroll
    for (int st = 0; st < 4; ++st) {
      sa[st] = __builtin_amdgcn_mfma_f32_16x16x32_bf16(kf[st][0], qf0, z, 0, 0, 0);
      sa[st] = __builtin_amdgcn_mfma_f32_16x16x32_bf16(kf[st][1], qf1, sa[st], 0, 0, 0);
    }
    float t[16];
    float tm = -1.0e30f;
    #pragma unroll
    for (int st = 0; st < 4; ++st)
      #pragma unroll
      for (int r = 0; r < 4; ++r) {
        float v = sa[st][r] * CSC;
        t[st * 4 + r] = v;
        tm = fmaxf(tm, v);
      }
    // defer-max: per-lane partial bound; rescale path (rare) does the row reduce
    if (!__all(tm - m2 <= 4.0f)) {
      tm = fmaxf(tm, __shfl_xor(tm, 16, 64));
      tm = fmaxf(tm, __shfl_xor(tm, 32, 64));
      float mn = fmaxf(m2, tm);
      float alpha = exp2f(m2 - mn);
      l_run *= alpha;
      #pragma unroll
      for (int dt = 0; dt < 4; ++dt)
        #pragma unroll
        for (int r = 0; r < 4; ++r) oacc[dt][r] *= alpha;
      m2 = mn;
    }
    float ps = 0.f;
    uint32_t pk[8];
    #pragma unroll
    for (int i = 0; i < 8; ++i) {
      float p0 = exp2f(t[2 * i] - m2);
      float p1 = exp2f(t[2 * i + 1] - m2);
      ps += p0 + p1;
      pk[i] = pack_bf2(p0, p1);
    }
    l_run += ps;
    #pragma unroll
    for (int st = 0; st < 4; ++st) {
      *(uint32_t*)&Pw[qi * 72 + st * 16 + g * 4] = pk[st * 2];
      *(uint32_t*)&Pw[qi * 72 + st * 16 + g * 4 + 2] = pk[st * 2 + 1];
    }
    short8 pB0 = *(const short8*)&Pw[qi * 72 + g * 8];
    short8 pB1 = *(const short8*)&Pw[qi * 72 + 32 + g * 8];
    #pragma unroll
    for (int dt = 0; dt < 4; ++dt) {
      oacc[dt] = __builtin_amdgcn_mfma_f32_16x16x32_bf16(vf0[dt], pB0, oacc[dt], 0, 0, 0);
      oacc[dt] = __builtin_amdgcn_mfma_f32_16x16x32_bf16(vf1[dt], pB1, oacc[dt], 0, 0, 0);
    }
  }

  // ---- masked 32-key tail (1 or 2 iterations) ----
  int k0t = qw & ~63;
  int ntail = ((qw & 63) + 16 + 31) >> 5;
  for (int tt = 0; tt < ntail; ++tt) {
    int k0 = k0t + tt * 32;
    unsigned short* Pw = &P[w][(nfull + tt) & 1][0];
    short8 kf00 = *(const short8*)&Kb[(size_t)(k0 + qi) * 64 + g * 8];
    short8 kf01 = *(const short8*)&Kb[(size_t)(k0 + qi) * 64 + g * 8 + 32];
    short8 kf10 = *(const short8*)&Kb[(size_t)(k0 + 16 + qi) * 64 + g * 8];
    short8 kf11 = *(const short8*)&Kb[(size_t)(k0 + 16 + qi) * 64 + g * 8 + 32];
    short8 vf[4];
    #pragma unroll
    for (int dt = 0; dt < 4; ++dt)
      vf[dt] = *(const short8*)&Vb[(size_t)(dt * 16 + qi) * SEQ + k0 + g * 8];
    f32x4 s0 = __builtin_amdgcn_mfma_f32_16x16x32_bf16(kf00, qf0, z, 0, 0, 0);
    s0 = __builtin_amdgcn_mfma_f32_16x16x32_bf16(kf01, qf1, s0, 0, 0, 0);
    f32x4 s1 = __builtin_amdgcn_mfma_f32_16x16x32_bf16(kf10, qf0, z, 0, 0, 0);
    s1 = __builtin_amdgcn_mfma_f32_16x16x32_bf16(kf11, qf1, s1, 0, 0, 0);
    float t[8];
    float tm = -1.0e30f;
    #pragma unroll
    for (int r = 0; r < 4; ++r) {
      int key0 = k0 + g * 4 + r;
      float v0 = (key0 <= qrow) ? s0[r] * CSC : -1.0e30f;
      float v1 = (key0 + 16 <= qrow) ? s1[r] * CSC : -1.0e30f;
      t[r] = v0; t[4 + r] = v1;
      tm = fmaxf(tm, fmaxf(v0, v1));
    }
    if (!__all(tm - m2 <= 4.0f)) {
      tm = fmaxf(tm, __shfl_xor(tm, 16, 64));
      tm = fmaxf(tm, __shfl_xor(tm, 32, 64));
      float mn = fmaxf(m2, tm);
      float alpha = exp2f(m2 - mn);
      l_run *= alpha;
      #pragma unroll
      for (int dt = 0; dt < 4; ++dt)
        #pragma unroll
        for (int r = 0; r < 4; ++r) oacc[dt][r] *= alpha;
      m2 = mn;
    }
    float ps = 0.f;
    uint32_t pk[4];
    #pragma unroll
    for (int i = 0; i < 4; ++i) {
      float p0 = exp2f(t[2 * i] - m2);
      float p1 = exp2f(t[2 * i + 1] - m2);
      ps += p0 + p1;
      pk[i] = pack_bf2(p0, p1);
    }
    l_run += ps;
    #pragma unroll
    for (int st = 0; st < 2; ++st) {
      *(uint32_t*)&Pw[qi * 72 + st * 16 + g * 4] = pk[st * 2];
      *(uint32_t*)&Pw[qi * 72 + st * 16 + g * 4 + 2] = pk[st * 2 + 1];
    }
    short8 pB = *(const short8*)&Pw[qi * 72 + g * 8];
    #pragma unroll
    for (int dt = 0; dt < 4; ++dt)
      oacc[dt] = __builtin_amdgcn_mfma_f32_16x16x32_bf16(vf[dt], pB, oacc[dt], 0, 0, 0);
  }

  // one-time l reduce across the 4 lane-groups of each q-row
  l_run += __shfl_xor(l_run, 16, 64);
  l_run += __shfl_xor(l_run, 32, 64);
  float inv = 1.0f / l_run;
  int b = bh >> 4, h = bh & 15;
  size_t rowbase = ((size_t)(b * SEQ + qw + qi)) * 1024 + h * 64;
  #pragma unroll
  for (int dt = 0; dt < 4; ++dt) {
    ushort4 o;
    o.x = f2bf(oacc[dt][0] * inv);
    o.y = f2bf(oacc[dt][1] * inv);
    o.z = f2bf(oacc[dt][2] * inv);
    o.w = f2bf(oacc[dt][3] * inv);
    *(ushort4*)&a_out[rowbase + dt * 16 + g * 4] = o;
  }
}

// ---------------- launch ----------------
extern "C" void kernel_launch(void* const* d_in, const int* in_sizes, int n_in,
                              void* d_out, int out_size, void* d_ws, size_t ws_size,
                              hipStream_t stream) {
  const float* x      = (const float*)d_in[0];
  const float* w_attn = (const float*)d_in[1];
  const float* b_attn = (const float*)d_in[2];
  const float* w_proj = (const float*)d_in[3];
  const float* b_proj = (const float*)d_in[4];
  float* out = (float*)d_out;
  char* ws = (char*)d_ws;
  // ws layout (48 MB total)
  unsigned short* x_bf  = (unsigned short*)(ws);               //  8 MB
  unsigned short* waT   = (unsigned short*)(ws + 8388608);     //  6 MB
  unsigned short* wpT   = (unsigned short*)(ws + 14680064);    //  2 MB
  unsigned short* q_ws  = (unsigned short*)(ws + 16777216);    //  8 MB
  unsigned short* k_ws  = (unsigned short*)(ws + 25165824);    //  8 MB
  unsigned short* vT_ws = (unsigned short*)(ws + 33554432);    //  8 MB
  unsigned short* a_ws  = (unsigned short*)(ws + 41943040);    //  8 MB

  hipLaunchKernelGGL(k_cvt, dim3(4096), dim3(256), 0, stream, x, x_bf, 4194304 / 4);
  hipLaunchKernelGGL(k_tcvt, dim3(48, 16), dim3(256), 0, stream, w_attn, waT, 1024, 3072);
  hipLaunchKernelGGL(k_tcvt, dim3(16, 16), dim3(256), 0, stream, w_proj, wpT, 1024, 1024);
  hipLaunchKernelGGL(k_gemm_qkv, dim3(768), dim3(256), 0, stream,
                     x_bf, waT, b_attn, out, q_ws, k_ws, vT_ws);
  hipLaunchKernelGGL(k_attn, dim3(512), dim3(512), 0, stream, q_ws, k_ws, vT_ws, a_ws);
  hipLaunchKernelGGL(k_gemm_proj, dim3(256), dim3(256), 0, stream, a_ws, wpT, b_proj, out);
}